// Round 6
// baseline (88.800 us; speedup 1.0000x reference)
//
#include <hip/hip_runtime.h>

#define NATOMS 8192
#define MAXP (64 * NATOMS) /* 524288 */
#define R2CUT 25.0f

constexpr int NC1 = 9;                  // cells per axis (45/5)
constexpr int NCELL = NC1 * NC1 * NC1;  // 729
constexpr int BCAP = 48;                // bucket capacity (max cell occupancy ~28)
constexpr int ROWW = 128;               // per-row neighbor capacity

// Pair predicate must match float32 numpy bit-exactly: no FMA contraction.
__device__ __forceinline__ float d2_exact(float dx, float dy, float dz) {
    return __fadd_rn(__fadd_rn(__fmul_rn(dx, dx), __fmul_rn(dy, dy)),
                     __fmul_rn(dz, dz));
}

// Double-precision cell assign: monotone; cells >=2 apart => d2 >= 25 exactly.
__device__ __forceinline__ int cellOf(float v) {
    int c = (int)((double)v * 0.2);
    return c < 0 ? 0 : (c > NC1 - 1 ? NC1 - 1 : c);
}

// ---------------------------------------------------------------------------
// 256 blocks x 256: (a) blanket-write the padded output (12.6 MB, coalesced);
// (b) bin one atom per thread into padded per-cell buckets via global atomics
// (bucketCount pre-zeroed by hipMemsetAsync).
__global__ __launch_bounds__(256) void bin_par(const float* __restrict__ pos,
                                               int* __restrict__ bucketCount,
                                               float4* __restrict__ buckets,
                                               float4* __restrict__ out4) {
    const int g = blockIdx.x * 256 + threadIdx.x;  // 0..65535
    const float4 negv  = make_float4(-1.f, -1.f, -1.f, -1.f);
    const float4 zerov = make_float4(0.f, 0.f, 0.f, 0.f);
    // 786432 float4 total; first 262144 (edge_index region) -> -1, rest -> 0
#pragma unroll
    for (int k = 0; k < 12; ++k) {
        const int idx = g + k * 65536;
        out4[idx] = (idx < 262144) ? negv : zerov;
    }
    if (g < NATOMS) {
        const float x = pos[3 * g], y = pos[3 * g + 1], z = pos[3 * g + 2];
        const int c = (cellOf(z) * NC1 + cellOf(y)) * NC1 + cellOf(x);
        const int slot = atomicAdd(&bucketCount[c], 1);
        if (slot < BCAP)
            buckets[c * BCAP + slot] = make_float4(x, y, z, __int_as_float(g));
    }
}

// ---------------------------------------------------------------------------
// One wave per row i. All 27 neighbor-cell counts are loaded up-front (one
// independent batch -> one waitcnt), then 9 packed candidate runs. Hits OR
// into a per-wave 8192-bit LDS bitmap, emitted ascending-j (canonical order,
// matches jnp.nonzero row-major).
__global__ __launch_bounds__(512) void nl_neigh(const float* __restrict__ pos,
                                                const int* __restrict__ batch,
                                                const int* __restrict__ bucketCount,
                                                const float4* __restrict__ buckets,
                                                int* __restrict__ counts,
                                                unsigned short* __restrict__ rowbuf) {
    __shared__ unsigned int bm[8][256];  // 8 KB, private per wave
    const int t = threadIdx.x;
    const int lane = t & 63;
    const int wave = t >> 6;
    const int i = blockIdx.x * 8 + wave;
    unsigned int* sb = bm[wave];
    sb[lane] = 0u; sb[lane + 64] = 0u; sb[lane + 128] = 0u; sb[lane + 192] = 0u;

    const float xi = pos[3 * i], yi = pos[3 * i + 1], zi = pos[3 * i + 2];
    const int bi = batch[i];
    const int cx = cellOf(xi), cy = cellOf(yi), cz = cellOf(zi);
    const int xlo = cx > 0 ? cx - 1 : 0;
    const int nc = (cx < NC1 - 1 ? cx + 1 : NC1 - 1) - xlo + 1;

    // Hoist: enumerate the 9 (dz,dy) runs and load all counts in one batch.
    int c0a[9], n0a[9], n1a[9], n2a[9];
#pragma unroll
    for (int r = 0; r < 9; ++r) {
        const int czz = cz + r / 3 - 1;
        const int cyy = cy + r % 3 - 1;
        const bool v = ((unsigned)czz < (unsigned)NC1) &&
                       ((unsigned)cyy < (unsigned)NC1);
        c0a[r] = v ? (czz * NC1 + cyy) * NC1 + xlo : 0;
        n0a[r] = v ? 1 : 0;  // validity marker, replaced below
    }
#pragma unroll
    for (int r = 0; r < 9; ++r) {
        const bool v = n0a[r] != 0;
        n0a[r] = v ? min(bucketCount[c0a[r]], BCAP) : 0;
        n1a[r] = (v && nc > 1) ? min(bucketCount[c0a[r] + 1], BCAP) : 0;
        n2a[r] = (v && nc > 2) ? min(bucketCount[c0a[r] + 2], BCAP) : 0;
    }

#pragma unroll
    for (int r = 0; r < 9; ++r) {
        const int n0 = n0a[r], n1 = n1a[r], n2 = n2a[r];
        const int m = n0 + n1 + n2;
        const int c0 = c0a[r];
        for (int k = lane; k < m; k += 64) {
            int cell, idx;
            if (k < n0)           { cell = c0;     idx = k; }
            else if (k < n0 + n1) { cell = c0 + 1; idx = k - n0; }
            else                  { cell = c0 + 2; idx = k - n0 - n1; }
            const float4 p = buckets[cell * BCAP + idx];
            const int j = __float_as_int(p.w);
            const float dxv = xi - p.x;
            const float dyv = yi - p.y;
            const float dzv = zi - p.z;
            const float d2 = d2_exact(dxv, dyv, dzv);
            if (d2 < R2CUT && j != i && batch[j] == bi)
                atomicOr(&sb[j >> 5], 1u << (j & 31));
        }
    }

    // Emit ascending-j u16 list to global rowbuf.
    unsigned short* rb = rowbuf + (size_t)i * ROWW;
    int total = 0;
#pragma unroll
    for (int g = 0; g < 4; ++g) {
        unsigned int w = sb[g * 64 + lane];
        const int c = __popc(w);
        int incl = c;
        for (int off = 1; off < 64; off <<= 1) {
            const int u = __shfl_up(incl, off);
            if (lane >= off) incl += u;
        }
        int o = total + incl - c;  // exclusive within row
        const unsigned int jbase = (unsigned)(g * 64 + lane) * 32u;
        while (w) {
            const int bit = __ffs(w) - 1;
            w &= w - 1u;
            if (o < ROWW) rb[o] = (unsigned short)(jbase + (unsigned)bit);
            ++o;
        }
        total += __shfl(incl, 63);
    }
    if (lane == 0) counts[i] = total > ROWW ? ROWW : total;
}

// ---------------------------------------------------------------------------
// 256 blocks x 512. Each block redundantly scans all 8192 counts (32 KB,
// L2-resident) for its own 32 rows' offsets, then scatters compacted edge
// data over the pre-written padding.
__global__ __launch_bounds__(512) void nl_scatter(const float* __restrict__ pos,
                                                  const unsigned short* __restrict__ rowbuf,
                                                  const int* __restrict__ counts,
                                                  float* __restrict__ out) {
    constexpr int NTHR = 512;
    __shared__ int partial[NTHR];
    __shared__ int rowoff[32];
    const int t = threadIdx.x;
    const int b = blockIdx.x;
    const int lane = t & 63;
    const int wave = t >> 6;

    const int4* c4 = (const int4*)counts;
    int4 v0 = c4[4 * t + 0], v1 = c4[4 * t + 1];
    int4 v2 = c4[4 * t + 2], v3 = c4[4 * t + 3];
    const int s = v0.x + v0.y + v0.z + v0.w + v1.x + v1.y + v1.z + v1.w +
                  v2.x + v2.y + v2.z + v2.w + v3.x + v3.y + v3.z + v3.w;
    partial[t] = s;
    __syncthreads();
    for (int off = 1; off < NTHR; off <<= 1) {
        const int u = (t >= off) ? partial[t - off] : 0;
        __syncthreads();
        partial[t] += u;
        __syncthreads();
    }
    // block b's rows 32b..32b+31 are exactly count-chunks t=2b and t=2b+1
    if ((t >> 1) == b) {
        int vals[16];
        vals[0] = v0.x;  vals[1] = v0.y;  vals[2] = v0.z;  vals[3] = v0.w;
        vals[4] = v1.x;  vals[5] = v1.y;  vals[6] = v1.z;  vals[7] = v1.w;
        vals[8] = v2.x;  vals[9] = v2.y;  vals[10] = v2.z; vals[11] = v2.w;
        vals[12] = v3.x; vals[13] = v3.y; vals[14] = v3.z; vals[15] = v3.w;
        const int qb = (t & 1) * 16;
        int run = partial[t] - s;  // exclusive prefix of counts[16t]
#pragma unroll
        for (int q = 0; q < 16; ++q) { rowoff[qb + q] = run; run += vals[q]; }
    }
    __syncthreads();

    float* __restrict__ outI = out;
    float* __restrict__ outJ = out + MAXP;
    float* __restrict__ outW = out + 2 * MAXP;
    float* __restrict__ outV = out + 3 * MAXP;

    for (int rr = 0; rr < 4; ++rr) {
        const int q = wave * 4 + rr;
        const int i = b * 32 + q;
        const int cnt = counts[i];
        const int base = rowoff[q];
        const float xi = pos[3 * i], yi = pos[3 * i + 1], zi = pos[3 * i + 2];
        const float fi = (float)i;
        const unsigned short* rb = rowbuf + (size_t)i * ROWW;
        for (int k = lane; k < cnt; k += 64) {
            const int j = rb[k];
            const float dxv = xi - pos[3 * j];
            const float dyv = yi - pos[3 * j + 1];
            const float dzv = zi - pos[3 * j + 2];
            const float d2 = d2_exact(dxv, dyv, dzv);
            const int slot = base + k;
            if (slot < MAXP) {
                outI[slot] = fi;
                outJ[slot] = (float)j;
                outW[slot] = sqrtf(d2);
                outV[3 * slot + 0] = dxv;
                outV[3 * slot + 1] = dyv;
                outV[3 * slot + 2] = dzv;
            }
        }
    }
}

// ---------------------------------------------------------------------------
extern "C" void kernel_launch(void* const* d_in, const int* in_sizes, int n_in,
                              void* d_out, int out_size, void* d_ws, size_t ws_size,
                              hipStream_t stream) {
    const float* pos = (const float*)d_in[0];
    const int* batch = (const int*)d_in[1];
    float* out = (float*)d_out;

    char* ws = (char*)d_ws;
    int* counts            = (int*)ws;                        // 32 KB
    int* bucketCount       = (int*)(ws + (32 << 10));         // 4 KB
    float4* buckets        = (float4*)(ws + (64 << 10));      // 560 KB
    unsigned short* rowbuf = (unsigned short*)(ws + (640 << 10));  // 2 MB

    hipMemsetAsync(bucketCount, 0, NCELL * sizeof(int), stream);
    bin_par<<<256, 256, 0, stream>>>(pos, bucketCount, buckets, (float4*)out);
    nl_neigh<<<NATOMS / 8, 512, 0, stream>>>(pos, batch, bucketCount, buckets,
                                             counts, rowbuf);
    nl_scatter<<<256, 512, 0, stream>>>(pos, rowbuf, counts, out);
}